// Round 5
// baseline (48.504 us; speedup 1.0000x reference)
//
#include <hip/hip_runtime.h>
#include <math.h>

#define NE 16
#define ND 5
#define NB 8
#define NP 65536
#define EDIM 128
#define NBETAS 4

typedef float f32x4 __attribute__((ext_vector_type(4)));

// Fused single kernel. Block = 256 threads = 4 expert-groups x 64 p-quads.
//   tid&63  -> p-quad slot (wave-contiguous, 1 KB per V load instruction)
//   tid>>6  -> expert group g, experts [4g, 4g+4)
// 2048 blocks; __launch_bounds__(256,6) forces >=6 waves/SIMD (24 waves/CU)
// for read-concurrency (TLP) — the R3/R4 plateau at 4 waves/SIMD measured
// ~5.15 TB/s; this trades per-thread ILP (20 loads) for 1.5x more waves.
// Prologue is per-wave (shfl only): w[e], scale, mask-dtype flag.
//   flag: 0 = 1-byte bool/uint8, 1 = int32, 2 = float32

__global__ __launch_bounds__(256, 6) void cfa_fused(
    const float* __restrict__ V,
    const void* __restrict__ masks,
    const float* __restrict__ betas,
    const float* __restrict__ embed,
    const float* __restrict__ temp,
    float* __restrict__ out)
{
    __shared__ float4 redA[3 * 64];
    __shared__ float4 redD[3 * 64];

    const int tid  = threadIdx.x;
    const int lane = tid & 63;
    const int s    = tid & 63;        // quad slot
    const int g    = tid >> 6;        // expert group 0..3
    const int e0   = g << 2;          // first expert of group (wave-uniform)

    const int q = blockIdx.x * 64 + s;          // global p-quad id [0, 131072)
    const int b = q >> 14;                      // NP/4 = 16384 quads per b
    const int p = (q & 16383) << 2;

    // ---- issue first expert's V loads immediately (depend on nothing) ----
    const float* vb  = V + b * NP + p;
    const float* ve0 = vb + e0 * (ND * NB * NP);
    f32x4 pre[ND];
    #pragma unroll
    for (int d = 0; d < ND; ++d)
        pre[d] = __builtin_nontemporal_load((const f32x4*)(ve0 + d * (NB * NP)));

    // ---- per-wave prologue (no barrier) ----
    // mask dtype flag from first 256 B. bool/u8 0/1: some byte1 nonzero.
    // f32 1.0 LE = 00 00 80 3F: byte3 nonzero. int32 0/1 LE: bytes 1,3 zero.
    unsigned mx = ((const unsigned*)masks)[lane];
    unsigned o1 = mx & 0x0000FF00u, o3 = mx & 0xFF000000u;
    #pragma unroll
    for (int off = 32; off; off >>= 1) {
        o1 |= __shfl_xor(o1, off, 64);
        o3 |= __shfl_xor(o3, off, 64);
    }
    const int flag = o1 ? 0 : (o3 ? 2 : 1);

    // w[e]: 4 lanes per expert (e = lane>>2, r = lane&3), then gather 4.
    float wv[4];
    {
        const int e = lane >> 2, r = lane & 3;
        const float4* ep = (const float4*)(embed + e * EDIM + r * 32);
        float sacc = 0.f;
        #pragma unroll
        for (int i = 0; i < 8; ++i) { float4 v = ep[i]; sacc += v.x + v.y + v.z + v.w; }
        sacc += __shfl_xor(sacc, 1, 64);
        sacc += __shfl_xor(sacc, 2, 64);
        float bsig = 1.f / (1.f + __expf(-betas[e * NBETAS + r]));
        bsig += __shfl_xor(bsig, 1, 64);
        bsig += __shfl_xor(bsig, 2, 64);
        float pos_w = 1.f / (1.f + __expf(-sacc * (1.f / EDIM)));
        float wfull = pos_w * (1.f + bsig * (1.f / NBETAS));
        #pragma unroll
        for (int ee = 0; ee < 4; ++ee)
            wv[ee] = __shfl(wfull, (e0 + ee) << 2, 64);
    }

    const float scale = 0.2f / fabsf(temp[0]);

    // ---- masks for this thread's 4 experts ----
    float4 wm[4];
    if (flag == 0) {
        const unsigned char* mb = (const unsigned char*)masks + p;
        #pragma unroll
        for (int ee = 0; ee < 4; ++ee) {
            uchar4 u = *(const uchar4*)(mb + (e0 + ee) * NP);
            wm[ee].x = wv[ee] * (float)u.x; wm[ee].y = wv[ee] * (float)u.y;
            wm[ee].z = wv[ee] * (float)u.z; wm[ee].w = wv[ee] * (float)u.w;
        }
    } else if (flag == 1) {
        const int* mi = (const int*)masks + p;
        #pragma unroll
        for (int ee = 0; ee < 4; ++ee) {
            int4 u = *(const int4*)(mi + (e0 + ee) * NP);
            wm[ee].x = wv[ee] * (float)u.x; wm[ee].y = wv[ee] * (float)u.y;
            wm[ee].z = wv[ee] * (float)u.z; wm[ee].w = wv[ee] * (float)u.w;
        }
    } else {
        const float* mf = (const float*)masks + p;
        #pragma unroll
        for (int ee = 0; ee < 4; ++ee) {
            float4 u = *(const float4*)(mf + (e0 + ee) * NP);
            wm[ee].x = wv[ee] * u.x; wm[ee].y = wv[ee] * u.y;
            wm[ee].z = wv[ee] * u.z; wm[ee].w = wv[ee] * u.w;
        }
    }

    float4 den = {0.f, 0.f, 0.f, 0.f};
    #pragma unroll
    for (int ee = 0; ee < 4; ++ee) {
        den.x += wm[ee].x; den.y += wm[ee].y;
        den.z += wm[ee].z; den.w += wm[ee].w;
    }

    // ---- consume prefetched expert e0, then stream the remaining 3 ----
    float4 a = {0.f, 0.f, 0.f, 0.f};
    #pragma unroll
    for (int d = 0; d < ND; ++d) {
        a.x = fmaf(wm[0].x, pre[d].x, a.x);
        a.y = fmaf(wm[0].y, pre[d].y, a.y);
        a.z = fmaf(wm[0].z, pre[d].z, a.z);
        a.w = fmaf(wm[0].w, pre[d].w, a.w);
    }
    #pragma unroll
    for (int ee = 1; ee < 4; ++ee) {
        const float* ve = vb + (e0 + ee) * (ND * NB * NP);
        #pragma unroll
        for (int d = 0; d < ND; ++d) {
            f32x4 v = __builtin_nontemporal_load((const f32x4*)(ve + d * (NB * NP)));
            a.x = fmaf(wm[ee].x, v.x, a.x);
            a.y = fmaf(wm[ee].y, v.y, a.y);
            a.z = fmaf(wm[ee].z, v.z, a.z);
            a.w = fmaf(wm[ee].w, v.w, a.w);
        }
    }

    // ---- combine 4 group-partials via LDS; group 0 finalizes ----
    if (g > 0) {
        redA[(g - 1) * 64 + s] = a;
        redD[(g - 1) * 64 + s] = den;
    }
    __syncthreads();
    if (g == 0) {
        #pragma unroll
        for (int k = 0; k < 3; ++k) {
            float4 a2 = redA[k * 64 + s], d2 = redD[k * 64 + s];
            a.x += a2.x; a.y += a2.y; a.z += a2.z; a.w += a2.w;
            den.x += d2.x; den.y += d2.y; den.z += d2.z; den.w += d2.w;
        }
        float4 o;
        o.x = a.x / fmaxf(den.x, 1e-6f) * scale;
        o.y = a.y / fmaxf(den.y, 1e-6f) * scale;
        o.z = a.z / fmaxf(den.z, 1e-6f) * scale;
        o.w = a.w / fmaxf(den.w, 1e-6f) * scale;
        *(float4*)(out + b * NP + p) = o;
    }
}

extern "C" void kernel_launch(void* const* d_in, const int* in_sizes, int n_in,
                              void* d_out, int out_size, void* d_ws, size_t ws_size,
                              hipStream_t stream) {
    const float* V     = (const float*)d_in[0];
    const void*  masks = d_in[1];
    const float* betas = (const float*)d_in[2];
    const float* embed = (const float*)d_in[3];
    const float* temp  = (const float*)d_in[4];

    float* out = (float*)d_out;

    const int blocks = (NB * NP / 4) / 64;   // 2048
    cfa_fused<<<blocks, 256, 0, stream>>>(V, masks, betas, embed, temp, out);
}

// Round 6
// 44.038 us; speedup vs baseline: 1.1014x; 1.1014x over previous
//
#include <hip/hip_runtime.h>
#include <math.h>

#define NE 16
#define ND 5
#define NB 8
#define NP 65536
#define EDIM 128
#define NBETAS 4

typedef float f32x4 __attribute__((ext_vector_type(4)));

// Fused single kernel. Block = 512 threads = 8 expert-groups x 64 p-quads.
//   tid&63 -> p-quad slot (wave-contiguous, 1 KB per V load instruction)
//   tid>>6 -> expert group g (0..7), experts {2g, 2g+1}
// Slim threads (10 in-flight float4 ~= 40 VGPRs of load data) so that
// __launch_bounds__(512,6) (84-VGPR cap) raises occupancy to 24 waves/CU
// WITHOUT spilling (R5's mistake: 20-deep loads under an 84-VGPR cap ->
// scratch spill -> +46% traffic). Tests the read-concurrency theory of the
// 5.2 TB/s plateau.
// Prologue per-wave (shfl only): w[e], scale, mask-dtype flag.
//   flag: 0 = 1-byte bool/uint8, 1 = int32, 2 = float32

__global__ __launch_bounds__(512, 6) void cfa_fused(
    const float* __restrict__ V,
    const void* __restrict__ masks,
    const float* __restrict__ betas,
    const float* __restrict__ embed,
    const float* __restrict__ temp,
    float* __restrict__ out)
{
    __shared__ float4 redA[7 * 64];
    __shared__ float4 redD[7 * 64];

    const int tid  = threadIdx.x;
    const int lane = tid & 63;
    const int s    = tid & 63;        // quad slot
    const int g    = tid >> 6;        // expert group 0..7
    const int e0   = g << 1;          // first expert of group (wave-uniform)

    const int q = blockIdx.x * 64 + s;          // global p-quad id [0, 131072)
    const int b = q >> 14;                      // NP/4 = 16384 quads per b
    const int p = (q & 16383) << 2;

    // ---- issue first expert's V loads immediately (depend on nothing) ----
    const float* vb  = V + b * NP + p;
    const float* ve0 = vb + e0 * (ND * NB * NP);
    f32x4 pre[ND];
    #pragma unroll
    for (int d = 0; d < ND; ++d)
        pre[d] = __builtin_nontemporal_load((const f32x4*)(ve0 + d * (NB * NP)));

    // ---- per-wave prologue (no barrier) ----
    // mask dtype flag from first 256 B. bool/u8 0/1: some byte1 nonzero.
    // f32 1.0 LE = 00 00 80 3F: byte3 nonzero. int32 0/1 LE: bytes 1,3 zero.
    unsigned mx = ((const unsigned*)masks)[lane];
    unsigned o1 = mx & 0x0000FF00u, o3 = mx & 0xFF000000u;
    #pragma unroll
    for (int off = 32; off; off >>= 1) {
        o1 |= __shfl_xor(o1, off, 64);
        o3 |= __shfl_xor(o3, off, 64);
    }
    const int flag = o1 ? 0 : (o3 ? 2 : 1);

    // w[e]: 4 lanes per expert (e = lane>>2, r = lane&3), then gather 2.
    float wv[2];
    {
        const int e = lane >> 2, r = lane & 3;
        const float4* ep = (const float4*)(embed + e * EDIM + r * 32);
        float sacc = 0.f;
        #pragma unroll
        for (int i = 0; i < 8; ++i) { float4 v = ep[i]; sacc += v.x + v.y + v.z + v.w; }
        sacc += __shfl_xor(sacc, 1, 64);
        sacc += __shfl_xor(sacc, 2, 64);
        float bsig = 1.f / (1.f + __expf(-betas[e * NBETAS + r]));
        bsig += __shfl_xor(bsig, 1, 64);
        bsig += __shfl_xor(bsig, 2, 64);
        float pos_w = 1.f / (1.f + __expf(-sacc * (1.f / EDIM)));
        float wfull = pos_w * (1.f + bsig * (1.f / NBETAS));
        wv[0] = __shfl(wfull, e0 << 2, 64);
        wv[1] = __shfl(wfull, (e0 + 1) << 2, 64);
    }

    const float scale = 0.2f / fabsf(temp[0]);

    // ---- masks for this thread's 2 experts ----
    float4 wm[2];
    if (flag == 0) {
        const unsigned char* mb = (const unsigned char*)masks + p;
        #pragma unroll
        for (int ee = 0; ee < 2; ++ee) {
            uchar4 u = *(const uchar4*)(mb + (e0 + ee) * NP);
            wm[ee].x = wv[ee] * (float)u.x; wm[ee].y = wv[ee] * (float)u.y;
            wm[ee].z = wv[ee] * (float)u.z; wm[ee].w = wv[ee] * (float)u.w;
        }
    } else if (flag == 1) {
        const int* mi = (const int*)masks + p;
        #pragma unroll
        for (int ee = 0; ee < 2; ++ee) {
            int4 u = *(const int4*)(mi + (e0 + ee) * NP);
            wm[ee].x = wv[ee] * (float)u.x; wm[ee].y = wv[ee] * (float)u.y;
            wm[ee].z = wv[ee] * (float)u.z; wm[ee].w = wv[ee] * (float)u.w;
        }
    } else {
        const float* mf = (const float*)masks + p;
        #pragma unroll
        for (int ee = 0; ee < 2; ++ee) {
            float4 u = *(const float4*)(mf + (e0 + ee) * NP);
            wm[ee].x = wv[ee] * u.x; wm[ee].y = wv[ee] * u.y;
            wm[ee].z = wv[ee] * u.z; wm[ee].w = wv[ee] * u.w;
        }
    }

    float4 den;
    den.x = wm[0].x + wm[1].x; den.y = wm[0].y + wm[1].y;
    den.z = wm[0].z + wm[1].z; den.w = wm[0].w + wm[1].w;

    // ---- consume prefetched expert e0, then stream expert e0+1 ----
    float4 a = {0.f, 0.f, 0.f, 0.f};
    #pragma unroll
    for (int d = 0; d < ND; ++d) {
        a.x = fmaf(wm[0].x, pre[d].x, a.x);
        a.y = fmaf(wm[0].y, pre[d].y, a.y);
        a.z = fmaf(wm[0].z, pre[d].z, a.z);
        a.w = fmaf(wm[0].w, pre[d].w, a.w);
    }
    {
        const float* ve = vb + (e0 + 1) * (ND * NB * NP);
        #pragma unroll
        for (int d = 0; d < ND; ++d) {
            f32x4 v = __builtin_nontemporal_load((const f32x4*)(ve + d * (NB * NP)));
            a.x = fmaf(wm[1].x, v.x, a.x);
            a.y = fmaf(wm[1].y, v.y, a.y);
            a.z = fmaf(wm[1].z, v.z, a.z);
            a.w = fmaf(wm[1].w, v.w, a.w);
        }
    }

    // ---- combine 8 group-partials via LDS; group 0 finalizes ----
    if (g > 0) {
        redA[(g - 1) * 64 + s] = a;
        redD[(g - 1) * 64 + s] = den;
    }
    __syncthreads();
    if (g == 0) {
        #pragma unroll
        for (int k = 0; k < 7; ++k) {
            float4 a2 = redA[k * 64 + s], d2 = redD[k * 64 + s];
            a.x += a2.x; a.y += a2.y; a.z += a2.z; a.w += a2.w;
            den.x += d2.x; den.y += d2.y; den.z += d2.z; den.w += d2.w;
        }
        float4 o;
        o.x = a.x / fmaxf(den.x, 1e-6f) * scale;
        o.y = a.y / fmaxf(den.y, 1e-6f) * scale;
        o.z = a.z / fmaxf(den.z, 1e-6f) * scale;
        o.w = a.w / fmaxf(den.w, 1e-6f) * scale;
        *(float4*)(out + b * NP + p) = o;
    }
}

extern "C" void kernel_launch(void* const* d_in, const int* in_sizes, int n_in,
                              void* d_out, int out_size, void* d_ws, size_t ws_size,
                              hipStream_t stream) {
    const float* V     = (const float*)d_in[0];
    const void*  masks = d_in[1];
    const float* betas = (const float*)d_in[2];
    const float* embed = (const float*)d_in[3];
    const float* temp  = (const float*)d_in[4];

    float* out = (float*)d_out;

    const int blocks = (NB * NP / 4) / 64;   // 2048
    cfa_fused<<<blocks, 512, 0, stream>>>(V, masks, betas, embed, temp, out);
}

// Round 7
// 37.450 us; speedup vs baseline: 1.2952x; 1.1759x over previous
//
#include <hip/hip_runtime.h>
#include <math.h>

#define NE 16
#define ND 5
#define NB 8
#define NP 65536
#define EDIM 128
#define NBETAS 4

typedef float f32x4 __attribute__((ext_vector_type(4)));

// R7 = R4 (33.2 us baseline: fat threads, 2-way expert split, barrier-free
// shfl prologue, NT loads, e0-prefetch, 4 waves/SIMD) + bijective
// XCD-chunked blockIdx swizzle. With 1024 blocks (1024 % 8 == 0), XCD k
// owns contiguous q in [k*16384,(k+1)*16384) == all of batch b=k, so each
// XCD reads 80 planes x one contiguous 256 KB slab instead of 2 KB
// fragments sprayed over 168 MB. Tests DRAM row/stream locality as the
// cause of the 5.16 TB/s read plateau (concurrency ruled out R5/R6).
//   flag: 0 = 1-byte bool/uint8, 1 = int32, 2 = float32

__global__ __launch_bounds__(256, 4) void cfa_fused(
    const float* __restrict__ V,
    const void* __restrict__ masks,
    const float* __restrict__ betas,
    const float* __restrict__ embed,
    const float* __restrict__ temp,
    float* __restrict__ out)
{
    __shared__ float4 redA[128];
    __shared__ float4 redD[128];

    const int tid  = threadIdx.x;
    const int lane = tid & 63;

    // ---- XCD-chunked bijective swizzle (gridDim.x = 1024, %8 == 0) ----
    const int bid = blockIdx.x;
    const int swz = (bid & 7) * 128 + (bid >> 3);   // xcd * cpx + chunk

    const int q  = swz * 128 + (tid & 127);         // global p-quad id [0, 131072)
    const int b  = q >> 14;                         // NP/4 = 16384 quads per b
    const int p  = (q & 16383) << 2;
    const int e0 = (tid >> 7) << 3;                 // 0 or 8 (wave-uniform)

    // ---- issue first expert's V loads immediately (depend on nothing) ----
    const float* vb  = V + b * NP + p;
    const float* ve0 = vb + e0 * (ND * NB * NP);
    f32x4 pre[ND];
    #pragma unroll
    for (int d = 0; d < ND; ++d)
        pre[d] = __builtin_nontemporal_load((const f32x4*)(ve0 + d * (NB * NP)));

    // ---- per-wave prologue (no barrier) ----
    // mask dtype flag from first 256 B. bool/u8 0/1: some byte1 nonzero.
    // f32 1.0 LE = 00 00 80 3F: byte3 nonzero. int32 0/1 LE: bytes 1,3 zero.
    unsigned mx = ((const unsigned*)masks)[lane];
    unsigned o1 = mx & 0x0000FF00u, o3 = mx & 0xFF000000u;
    #pragma unroll
    for (int off = 32; off; off >>= 1) {
        o1 |= __shfl_xor(o1, off, 64);
        o3 |= __shfl_xor(o3, off, 64);
    }
    const int flag = o1 ? 0 : (o3 ? 2 : 1);

    // w[e]: 4 lanes per expert (e = lane>>2, r = lane&3), then gather 8.
    float wv[8];
    {
        const int e = lane >> 2, r = lane & 3;
        const float4* ep = (const float4*)(embed + e * EDIM + r * 32);
        float sacc = 0.f;
        #pragma unroll
        for (int i = 0; i < 8; ++i) { float4 v = ep[i]; sacc += v.x + v.y + v.z + v.w; }
        sacc += __shfl_xor(sacc, 1, 64);
        sacc += __shfl_xor(sacc, 2, 64);
        float bsig = 1.f / (1.f + __expf(-betas[e * NBETAS + r]));
        bsig += __shfl_xor(bsig, 1, 64);
        bsig += __shfl_xor(bsig, 2, 64);
        float pos_w = 1.f / (1.f + __expf(-sacc * (1.f / EDIM)));
        float wfull = pos_w * (1.f + bsig * (1.f / NBETAS));
        #pragma unroll
        for (int ee = 0; ee < 8; ++ee)
            wv[ee] = __shfl(wfull, (e0 + ee) << 2, 64);
    }

    const float scale = 0.2f / fabsf(temp[0]);

    // ---- masks for this thread's 8 experts ----
    float4 wm[8];
    if (flag == 0) {
        const unsigned char* mb = (const unsigned char*)masks + p;
        #pragma unroll
        for (int ee = 0; ee < 8; ++ee) {
            uchar4 u = *(const uchar4*)(mb + (e0 + ee) * NP);
            wm[ee].x = wv[ee] * (float)u.x; wm[ee].y = wv[ee] * (float)u.y;
            wm[ee].z = wv[ee] * (float)u.z; wm[ee].w = wv[ee] * (float)u.w;
        }
    } else if (flag == 1) {
        const int* mi = (const int*)masks + p;
        #pragma unroll
        for (int ee = 0; ee < 8; ++ee) {
            int4 u = *(const int4*)(mi + (e0 + ee) * NP);
            wm[ee].x = wv[ee] * (float)u.x; wm[ee].y = wv[ee] * (float)u.y;
            wm[ee].z = wv[ee] * (float)u.z; wm[ee].w = wv[ee] * (float)u.w;
        }
    } else {
        const float* mf = (const float*)masks + p;
        #pragma unroll
        for (int ee = 0; ee < 8; ++ee) {
            float4 u = *(const float4*)(mf + (e0 + ee) * NP);
            wm[ee].x = wv[ee] * u.x; wm[ee].y = wv[ee] * u.y;
            wm[ee].z = wv[ee] * u.z; wm[ee].w = wv[ee] * u.w;
        }
    }

    float4 den = {0.f, 0.f, 0.f, 0.f};
    #pragma unroll
    for (int ee = 0; ee < 8; ++ee) {
        den.x += wm[ee].x; den.y += wm[ee].y;
        den.z += wm[ee].z; den.w += wm[ee].w;
    }

    // ---- consume prefetched expert e0, then stream the rest ----
    float4 a = {0.f, 0.f, 0.f, 0.f};
    #pragma unroll
    for (int d = 0; d < ND; ++d) {
        a.x = fmaf(wm[0].x, pre[d].x, a.x);
        a.y = fmaf(wm[0].y, pre[d].y, a.y);
        a.z = fmaf(wm[0].z, pre[d].z, a.z);
        a.w = fmaf(wm[0].w, pre[d].w, a.w);
    }
    #pragma unroll
    for (int ee = 1; ee < 8; ++ee) {
        const float* ve = vb + (e0 + ee) * (ND * NB * NP);
        #pragma unroll
        for (int d = 0; d < ND; ++d) {
            f32x4 v = __builtin_nontemporal_load((const f32x4*)(ve + d * (NB * NP)));
            a.x = fmaf(wm[ee].x, v.x, a.x);
            a.y = fmaf(wm[ee].y, v.y, a.y);
            a.z = fmaf(wm[ee].z, v.z, a.z);
            a.w = fmaf(wm[ee].w, v.w, a.w);
        }
    }

    // ---- combine halves via LDS, lower half finalizes ----
    if (tid >= 128) {
        redA[tid - 128] = a;
        redD[tid - 128] = den;
    }
    __syncthreads();
    if (tid < 128) {
        float4 a2 = redA[tid], d2 = redD[tid];
        a.x += a2.x; a.y += a2.y; a.z += a2.z; a.w += a2.w;
        den.x += d2.x; den.y += d2.y; den.z += d2.z; den.w += d2.w;
        float4 o;
        o.x = a.x / fmaxf(den.x, 1e-6f) * scale;
        o.y = a.y / fmaxf(den.y, 1e-6f) * scale;
        o.z = a.z / fmaxf(den.z, 1e-6f) * scale;
        o.w = a.w / fmaxf(den.w, 1e-6f) * scale;
        *(float4*)(out + b * NP + p) = o;
    }
}

extern "C" void kernel_launch(void* const* d_in, const int* in_sizes, int n_in,
                              void* d_out, int out_size, void* d_ws, size_t ws_size,
                              hipStream_t stream) {
    const float* V     = (const float*)d_in[0];
    const void*  masks = d_in[1];
    const float* betas = (const float*)d_in[2];
    const float* embed = (const float*)d_in[3];
    const float* temp  = (const float*)d_in[4];

    float* out = (float*)d_out;

    const int blocks = (NB * NP / 4) / 128;   // 1024
    cfa_fused<<<blocks, 256, 0, stream>>>(V, masks, betas, embed, temp, out);
}

// Round 8
// 34.035 us; speedup vs baseline: 1.4251x; 1.1004x over previous
//
#include <hip/hip_runtime.h>
#include <math.h>

#define NE 16
#define ND 5
#define NB 8
#define NP 65536
#define EDIM 128
#define NBETAS 4

typedef float f32x4 __attribute__((ext_vector_type(4)));

// R8 = R4 structure (2-way expert split, 40-deep dwordx4 stream, barrier-free
// shfl prologue, NT loads, e0-prefetch, NO xcd swizzle — R7 showed chunking
// regresses) with block = 512 threads over 256 contiguous p-quads:
// each (e,d) plane gets a 4 KB contiguous run per block (2x R4) to improve
// DRAM row locality of the 80-way interleaved read streams.
//   tid>>8 -> expert half (0..7 / 8..15), tid&255 -> p-quad slot.
// __launch_bounds__(512,2): 128-VGPR cap, 16 waves/CU — same as the 33.2 us
// baseline regime (R5/R6 showed tighter caps spill and regress).
//   flag: 0 = 1-byte bool/uint8, 1 = int32, 2 = float32

__global__ __launch_bounds__(512, 2) void cfa_fused(
    const float* __restrict__ V,
    const void* __restrict__ masks,
    const float* __restrict__ betas,
    const float* __restrict__ embed,
    const float* __restrict__ temp,
    float* __restrict__ out)
{
    __shared__ float4 redA[256];
    __shared__ float4 redD[256];

    const int tid  = threadIdx.x;
    const int lane = tid & 63;
    const int slot = tid & 255;                 // p-quad slot in block
    const int e0   = (tid >> 8) << 3;           // 0 or 8 (wave-uniform)

    const int q = blockIdx.x * 256 + slot;      // global p-quad id [0, 131072)
    const int b = q >> 14;                      // NP/4 = 16384 quads per b
    const int p = (q & 16383) << 2;

    // ---- issue first expert's V loads immediately (depend on nothing) ----
    const float* vb  = V + b * NP + p;
    const float* ve0 = vb + e0 * (ND * NB * NP);
    f32x4 pre[ND];
    #pragma unroll
    for (int d = 0; d < ND; ++d)
        pre[d] = __builtin_nontemporal_load((const f32x4*)(ve0 + d * (NB * NP)));

    // ---- per-wave prologue (no barrier) ----
    // mask dtype flag from first 256 B. bool/u8 0/1: some byte1 nonzero.
    // f32 1.0 LE = 00 00 80 3F: byte3 nonzero. int32 0/1 LE: bytes 1,3 zero.
    unsigned mx = ((const unsigned*)masks)[lane];
    unsigned o1 = mx & 0x0000FF00u, o3 = mx & 0xFF000000u;
    #pragma unroll
    for (int off = 32; off; off >>= 1) {
        o1 |= __shfl_xor(o1, off, 64);
        o3 |= __shfl_xor(o3, off, 64);
    }
    const int flag = o1 ? 0 : (o3 ? 2 : 1);

    // w[e]: 4 lanes per expert (e = lane>>2, r = lane&3), then gather 8.
    float wv[8];
    {
        const int e = lane >> 2, r = lane & 3;
        const float4* ep = (const float4*)(embed + e * EDIM + r * 32);
        float sacc = 0.f;
        #pragma unroll
        for (int i = 0; i < 8; ++i) { float4 v = ep[i]; sacc += v.x + v.y + v.z + v.w; }
        sacc += __shfl_xor(sacc, 1, 64);
        sacc += __shfl_xor(sacc, 2, 64);
        float bsig = 1.f / (1.f + __expf(-betas[e * NBETAS + r]));
        bsig += __shfl_xor(bsig, 1, 64);
        bsig += __shfl_xor(bsig, 2, 64);
        float pos_w = 1.f / (1.f + __expf(-sacc * (1.f / EDIM)));
        float wfull = pos_w * (1.f + bsig * (1.f / NBETAS));
        #pragma unroll
        for (int ee = 0; ee < 8; ++ee)
            wv[ee] = __shfl(wfull, (e0 + ee) << 2, 64);
    }

    const float scale = 0.2f / fabsf(temp[0]);

    // ---- masks for this thread's 8 experts ----
    float4 wm[8];
    if (flag == 0) {
        const unsigned char* mb = (const unsigned char*)masks + p;
        #pragma unroll
        for (int ee = 0; ee < 8; ++ee) {
            uchar4 u = *(const uchar4*)(mb + (e0 + ee) * NP);
            wm[ee].x = wv[ee] * (float)u.x; wm[ee].y = wv[ee] * (float)u.y;
            wm[ee].z = wv[ee] * (float)u.z; wm[ee].w = wv[ee] * (float)u.w;
        }
    } else if (flag == 1) {
        const int* mi = (const int*)masks + p;
        #pragma unroll
        for (int ee = 0; ee < 8; ++ee) {
            int4 u = *(const int4*)(mi + (e0 + ee) * NP);
            wm[ee].x = wv[ee] * (float)u.x; wm[ee].y = wv[ee] * (float)u.y;
            wm[ee].z = wv[ee] * (float)u.z; wm[ee].w = wv[ee] * (float)u.w;
        }
    } else {
        const float* mf = (const float*)masks + p;
        #pragma unroll
        for (int ee = 0; ee < 8; ++ee) {
            float4 u = *(const float4*)(mf + (e0 + ee) * NP);
            wm[ee].x = wv[ee] * u.x; wm[ee].y = wv[ee] * u.y;
            wm[ee].z = wv[ee] * u.z; wm[ee].w = wv[ee] * u.w;
        }
    }

    float4 den = {0.f, 0.f, 0.f, 0.f};
    #pragma unroll
    for (int ee = 0; ee < 8; ++ee) {
        den.x += wm[ee].x; den.y += wm[ee].y;
        den.z += wm[ee].z; den.w += wm[ee].w;
    }

    // ---- consume prefetched expert e0, then stream the rest ----
    float4 a = {0.f, 0.f, 0.f, 0.f};
    #pragma unroll
    for (int d = 0; d < ND; ++d) {
        a.x = fmaf(wm[0].x, pre[d].x, a.x);
        a.y = fmaf(wm[0].y, pre[d].y, a.y);
        a.z = fmaf(wm[0].z, pre[d].z, a.z);
        a.w = fmaf(wm[0].w, pre[d].w, a.w);
    }
    #pragma unroll
    for (int ee = 1; ee < 8; ++ee) {
        const float* ve = vb + (e0 + ee) * (ND * NB * NP);
        #pragma unroll
        for (int d = 0; d < ND; ++d) {
            f32x4 v = __builtin_nontemporal_load((const f32x4*)(ve + d * (NB * NP)));
            a.x = fmaf(wm[ee].x, v.x, a.x);
            a.y = fmaf(wm[ee].y, v.y, a.y);
            a.z = fmaf(wm[ee].z, v.z, a.z);
            a.w = fmaf(wm[ee].w, v.w, a.w);
        }
    }

    // ---- combine halves via LDS, lower half finalizes ----
    if (tid >= 256) {
        redA[slot] = a;
        redD[slot] = den;
    }
    __syncthreads();
    if (tid < 256) {
        float4 a2 = redA[slot], d2 = redD[slot];
        a.x += a2.x; a.y += a2.y; a.z += a2.z; a.w += a2.w;
        den.x += d2.x; den.y += d2.y; den.z += d2.z; den.w += d2.w;
        float4 o;
        o.x = a.x / fmaxf(den.x, 1e-6f) * scale;
        o.y = a.y / fmaxf(den.y, 1e-6f) * scale;
        o.z = a.z / fmaxf(den.z, 1e-6f) * scale;
        o.w = a.w / fmaxf(den.w, 1e-6f) * scale;
        *(float4*)(out + b * NP + p) = o;
    }
}

extern "C" void kernel_launch(void* const* d_in, const int* in_sizes, int n_in,
                              void* d_out, int out_size, void* d_ws, size_t ws_size,
                              hipStream_t stream) {
    const float* V     = (const float*)d_in[0];
    const void*  masks = d_in[1];
    const float* betas = (const float*)d_in[2];
    const float* embed = (const float*)d_in[3];
    const float* temp  = (const float*)d_in[4];

    float* out = (float*)d_out;

    const int blocks = (NB * NP / 4) / 256;   // 512
    cfa_fused<<<blocks, 512, 0, stream>>>(V, masks, betas, embed, temp, out);
}